// Round 2
// baseline (367.553 us; speedup 1.0000x reference)
//
#include <hip/hip_runtime.h>
#include <cstdint>
#include <cstddef>

typedef unsigned short u16;
typedef __attribute__((ext_vector_type(2))) unsigned short u16x2;
typedef __attribute__((ext_vector_type(4))) unsigned short u16x4;
typedef __attribute__((ext_vector_type(8))) unsigned short u16x8;
typedef __attribute__((ext_vector_type(8))) short s16x8;
typedef __attribute__((ext_vector_type(4))) float f32x4;

// fp32 -> bf16 round-to-nearest-even
__device__ __forceinline__ u16 f2bf(float f) {
  uint32_t u = __float_as_uint(f);
  u += 0x7fffu + ((u >> 16) & 1u);
  return (u16)(u >> 16);
}

__device__ __forceinline__ f32x4 mfma16(s16x8 a, s16x8 b, f32x4 c) {
  return __builtin_amdgcn_mfma_f32_16x16x32_bf16(a, b, c, 0, 0, 0);
}

#define GLDS16(gp, lp) __builtin_amdgcn_global_load_lds(                     \
    (const __attribute__((address_space(1))) void*)(gp),                      \
    (__attribute__((address_space(3))) void*)(lp), 16, 0, 0)

// ---------------- fp32 -> bf16 conversion ----------------
__global__ void cvt_f32_bf16(const float* __restrict__ in, u16* __restrict__ out, int n4) {
  int stride = gridDim.x * blockDim.x;
  for (int i = blockIdx.x * blockDim.x + threadIdx.x; i < n4; i += stride) {
    f32x4 v = ((const f32x4*)in)[i];
    u16x4 o;
    o[0] = f2bf(v[0]); o[1] = f2bf(v[1]); o[2] = f2bf(v[2]); o[3] = f2bf(v[3]);
    ((u16x4*)out)[i] = o;
  }
}

// ---------------- bf16 GEMM: C[M,N] = A[M,K] * B[N,K]^T + bias[N] ----------
// m97 structure: 128x128 tile, BK=32, 4 waves (2x2), 4x4 16x16x32 frags/wave,
// global_load_lds width-16 staging, 2 barriers per K-step.
// LDS map: lA rows 0..63 -> elements [0,2048), rows 64..127 -> [2048,4096).
template <int OUT_BF16>
__global__ __launch_bounds__(256, 2)
void gemm_bt(const u16* __restrict__ A, const u16* __restrict__ B,
             const float* __restrict__ bias, u16* __restrict__ Cb,
             float* __restrict__ Cf, int M, int N, int K, int tilesN) {
  __shared__ u16 lA[128 * 32];
  __shared__ u16 lB[128 * 32];

  // XCD-aware bijective swizzle (grid % 8 == 0 for both our GEMMs)
  int bid = blockIdx.x;
  int cpx = gridDim.x >> 3;
  bid = (bid & 7) * cpx + (bid >> 3);

  const int tm = bid / tilesN, tn = bid % tilesN;
  const int row0 = tm * 128, col0 = tn * 128;
  const int tid = threadIdx.x;
  const int lane = tid & 63, wave = tid >> 6;

  const u16* Ag = A + (size_t)(row0 + (tid >> 2)) * K + (tid & 3) * 8;
  const u16* Bg = B + (size_t)(col0 + (tid >> 2)) * K + (tid & 3) * 8;
  const int ldsoff = tid * 8;  // elements; *2 = bytes = tid*16

  const int wm = (wave >> 1) * 64, wn = (wave & 1) * 64;
  const int fr = lane & 15, fk = (lane >> 4) * 8;

  f32x4 acc[4][4] = {};

  for (int k0 = 0; k0 < K; k0 += 32) {
    __syncthreads();
    GLDS16(Ag + k0, &lA[ldsoff]);
    GLDS16(Ag + (size_t)64 * K + k0, &lA[2048 + ldsoff]);  // rows 64..127
    GLDS16(Bg + k0, &lB[ldsoff]);
    GLDS16(Bg + (size_t)64 * K + k0, &lB[2048 + ldsoff]);  // rows 64..127
    __syncthreads();

    s16x8 af[4], bfr[4];
#pragma unroll
    for (int i = 0; i < 4; ++i) af[i] = *(const s16x8*)&lA[(wm + i * 16 + fr) * 32 + fk];
#pragma unroll
    for (int i = 0; i < 4; ++i) bfr[i] = *(const s16x8*)&lB[(wn + i * 16 + fr) * 32 + fk];
#pragma unroll
    for (int i = 0; i < 4; ++i)
#pragma unroll
      for (int j = 0; j < 4; ++j) acc[i][j] = mfma16(af[i], bfr[j], acc[i][j]);
  }

  // epilogue: C row = (lane>>4)*4 + reg, col = lane&15 (per-frag)
#pragma unroll
  for (int i = 0; i < 4; ++i) {
#pragma unroll
    for (int r = 0; r < 4; ++r) {
      const int row = row0 + wm + i * 16 + (lane >> 4) * 4 + r;
#pragma unroll
      for (int j = 0; j < 4; ++j) {
        const int col = col0 + wn + j * 16 + fr;
        const float v = acc[i][j][r] + bias[col];
        if (OUT_BF16)
          Cb[(size_t)row * N + col] = f2bf(v);
        else
          Cf[(size_t)row * N + col] = v;
      }
    }
  }
}

// ---------------- causal flash attention -----------------------------------
// qkv: [B*T, 3072] bf16 where feature = s*1024 + h*64 + d
// out: [B*T, 1024] bf16 (feature = h*64 + d), i.e. "bqhd" layout
// Block: 4 waves; wave w owns q rows [qt*64 + 16w, +16). KV tiles of 32.
__global__ __launch_bounds__(256)
void attn_kernel(const u16* __restrict__ qkv, const unsigned char* __restrict__ pmask,
                 const float* __restrict__ scale_ptr, u16* __restrict__ outp) {
  __shared__ u16 lK[32 * 72];   // K tile [32 kv][64 hd] padded to 72
  __shared__ u16 lVt[64 * 48];  // V^T tile [64 hd][32 kv] padded to 48
  __shared__ u16 lP[4][16 * 48];  // per-wave P [16 q][32 kv] padded to 48
  __shared__ unsigned char lMask[1024];

  const int bid = blockIdx.x;
  const int qt = bid & 15;
  const int h = (bid >> 4) & 15;
  const int b = bid >> 8;
  const int tid = threadIdx.x;
  const int lane = tid & 63;
  const int wave = tid >> 6;
  const int fr = lane & 15;
  const int grp = lane >> 4;
  const float scale = scale_ptr[0];

  for (int i = tid; i < 1024; i += 256) lMask[i] = pmask[b * 1024 + i];

  const int qbase = qt * 64 + wave * 16;

  // Q fragments (B-operand): matrix row = q = fr, k = grp*8+j (+32 second chunk)
  s16x8 qf0, qf1;
  {
    const u16* qp = qkv + (size_t)(b * 1024 + qbase + fr) * 3072 + h * 64 + grp * 8;
    qf0 = *(const s16x8*)qp;
    qf1 = *(const s16x8*)(qp + 32);
  }

  f32x4 oacc[4] = {};
  float m_run = -1e30f, l_run = 0.0f;

  const int ntiles = qt * 2 + 2;
  const int qlast = qbase + 15;
  const int skv = tid >> 3;        // staging kv row 0..31
  const int sd = (tid & 7) * 8;    // staging hd chunk

  for (int t = 0; t < ntiles; ++t) {
    const int kvb = t * 32;
    __syncthreads();
    {
      const u16* kp = qkv + (size_t)(b * 1024 + kvb + skv) * 3072 + 1024 + h * 64 + sd;
      u16x8 kk = *(const u16x8*)kp;
      *(u16x8*)&lK[skv * 72 + sd] = kk;
      u16x8 vv = *(const u16x8*)(kp + 1024);
#pragma unroll
      for (int j = 0; j < 8; ++j) lVt[(sd + j) * 48 + skv] = vv[j];
    }
    __syncthreads();
    if (kvb > qlast) continue;  // tile fully above diagonal for this wave

    // S^T = K * Q^T : C[row=kv][col=q]
    f32x4 st[2];
#pragma unroll
    for (int f = 0; f < 2; ++f) {
      s16x8 a0 = *(const s16x8*)&lK[(f * 16 + fr) * 72 + grp * 8];
      s16x8 a1 = *(const s16x8*)&lK[(f * 16 + fr) * 72 + 32 + grp * 8];
      f32x4 acc = {0.0f, 0.0f, 0.0f, 0.0f};
      acc = mfma16(a0, qf0, acc);
      acc = mfma16(a1, qf1, acc);
      st[f] = acc;
    }

    const int q = qbase + fr;
    float sv[2][4];
    float tmax = -1e30f;
#pragma unroll
    for (int f = 0; f < 2; ++f)
#pragma unroll
      for (int r = 0; r < 4; ++r) {
        const int kv = kvb + f * 16 + grp * 4 + r;
        float v = st[f][r] * scale;
        v = (kv > q || lMask[kv]) ? -1e30f : v;
        sv[f][r] = v;
        tmax = fmaxf(tmax, v);
      }
    // row reduce across the 4 lane-groups holding the same q
    tmax = fmaxf(tmax, __shfl_xor(tmax, 16));
    tmax = fmaxf(tmax, __shfl_xor(tmax, 32));
    const float m_new = fmaxf(m_run, tmax);
    const float alpha = __expf(m_run - m_new);

    float rsum = 0.0f;
#pragma unroll
    for (int f = 0; f < 2; ++f)
#pragma unroll
      for (int rp = 0; rp < 2; ++rp) {
        const float p0 = __expf(sv[f][rp * 2 + 0] - m_new);
        const float p1 = __expf(sv[f][rp * 2 + 1] - m_new);
        rsum += p0 + p1;
        u16x2 pk;
        pk[0] = f2bf(p0);
        pk[1] = f2bf(p1);
        *(u16x2*)&lP[wave][fr * 48 + f * 16 + grp * 4 + rp * 2] = pk;
      }
    rsum += __shfl_xor(rsum, 16);
    rsum += __shfl_xor(rsum, 32);
    l_run = l_run * alpha + rsum;
    m_run = m_new;

    // per-output-row alphas (out C-layout row = grp*4 + r)
    float ar[4];
#pragma unroll
    for (int r = 0; r < 4; ++r) ar[r] = __shfl(alpha, grp * 4 + r);

    // PV: A-operand P[q=fr][kv=grp*8+j], B-operand V^T[hd=fr+16nf][kv=grp*8+j]
    s16x8 pa = *(const s16x8*)&lP[wave][fr * 48 + grp * 8];
#pragma unroll
    for (int nf = 0; nf < 4; ++nf) {
      s16x8 vb = *(const s16x8*)&lVt[(nf * 16 + fr) * 48 + grp * 8];
      f32x4 o = oacc[nf];
      o[0] *= ar[0];
      o[1] *= ar[1];
      o[2] *= ar[2];
      o[3] *= ar[3];
      oacc[nf] = mfma16(pa, vb, o);
    }
  }

  // epilogue: out row = q = grp*4 + r, col = hd = nf*16 + fr
  float linv[4];
#pragma unroll
  for (int r = 0; r < 4; ++r) linv[r] = 1.0f / __shfl(l_run, grp * 4 + r);
#pragma unroll
  for (int nf = 0; nf < 4; ++nf) {
    const int hd = nf * 16 + fr;
#pragma unroll
    for (int r = 0; r < 4; ++r) {
      const int tq = qbase + grp * 4 + r;
      outp[(size_t)(b * 1024 + tq) * 1024 + h * 64 + hd] = f2bf(oacc[nf][r] * linv[r]);
    }
  }
}

// ---------------- launch ----------------------------------------------------
extern "C" void kernel_launch(void* const* d_in, const int* in_sizes, int n_in,
                              void* d_out, int out_size, void* d_ws, size_t ws_size,
                              hipStream_t stream) {
  const float* x = (const float*)d_in[0];
  const unsigned char* pmask = (const unsigned char*)d_in[1];
  const float* Wqkv = (const float*)d_in[2];
  const float* bqkv = (const float*)d_in[3];
  const float* Wproj = (const float*)d_in[4];
  const float* bproj = (const float*)d_in[5];
  const float* scale = (const float*)d_in[6];
  float* out = (float*)d_out;

  // workspace layout (bytes)
  char* ws = (char*)d_ws;
  u16* xb     = (u16*)(ws + 0);          // 8192*1024*2  = 16,777,216
  u16* wqkvb  = (u16*)(ws + 16777216);   // 3072*1024*2  =  6,291,456
  u16* wprojb = (u16*)(ws + 23068672);   // 1024*1024*2  =  2,097,152
  u16* qkv    = (u16*)(ws + 25165824);   // 8192*3072*2  = 50,331,648
  u16* attno  = (u16*)(ws + 75497472);   // 8192*1024*2  = 16,777,216
  if (ws_size < (size_t)92274688) return;  // insufficient scratch -> fail loudly

  cvt_f32_bf16<<<2048, 256, 0, stream>>>(x, xb, 8 * 1024 * 1024 / 4);
  cvt_f32_bf16<<<1024, 256, 0, stream>>>(Wqkv, wqkvb, 3 * 1024 * 1024 / 4);
  cvt_f32_bf16<<<512, 256, 0, stream>>>(Wproj, wprojb, 1024 * 1024 / 4);

  // QKV = x @ Wqkv^T + b : [8192, 3072]
  gemm_bt<1><<<64 * 24, 256, 0, stream>>>(xb, wqkvb, bqkv, qkv, nullptr,
                                          8192, 3072, 1024, 24);
  // attention
  attn_kernel<<<2048, 256, 0, stream>>>(qkv, pmask, scale, attno);
  // out = attno @ Wproj^T + b : [8192, 1024] fp32
  gemm_bt<0><<<64 * 8, 256, 0, stream>>>(attno, wprojb, bproj, nullptr, out,
                                         8192, 1024, 1024, 8);
}

// Round 3
// 276.609 us; speedup vs baseline: 1.3288x; 1.3288x over previous
//
#include <hip/hip_runtime.h>
#include <cstdint>
#include <cstddef>

typedef unsigned short u16;
typedef __attribute__((ext_vector_type(2))) unsigned short u16x2;
typedef __attribute__((ext_vector_type(4))) unsigned short u16x4;
typedef __attribute__((ext_vector_type(8))) unsigned short u16x8;
typedef __attribute__((ext_vector_type(8))) short s16x8;
typedef __attribute__((ext_vector_type(4))) float f32x4;

// fp32 -> bf16 round-to-nearest-even
__device__ __forceinline__ u16 f2bf(float f) {
  uint32_t u = __float_as_uint(f);
  u += 0x7fffu + ((u >> 16) & 1u);
  return (u16)(u >> 16);
}

__device__ __forceinline__ f32x4 mfma16(s16x8 a, s16x8 b, f32x4 c) {
  return __builtin_amdgcn_mfma_f32_16x16x32_bf16(a, b, c, 0, 0, 0);
}

#define GLDS16(gp, lp) __builtin_amdgcn_global_load_lds(                     \
    (const __attribute__((address_space(1))) void*)(gp),                      \
    (__attribute__((address_space(3))) void*)(lp), 16, 0, 0)

// ---------------- fp32 -> bf16 conversion ----------------
__global__ void cvt_f32_bf16(const float* __restrict__ in, u16* __restrict__ out, int n4) {
  int stride = gridDim.x * blockDim.x;
  for (int i = blockIdx.x * blockDim.x + threadIdx.x; i < n4; i += stride) {
    f32x4 v = ((const f32x4*)in)[i];
    u16x4 o;
    o[0] = f2bf(v[0]); o[1] = f2bf(v[1]); o[2] = f2bf(v[2]); o[3] = f2bf(v[3]);
    ((u16x4*)out)[i] = o;
  }
}

// ---------------- bf16 GEMM: C[M,N] = A[M,K] * B[N,K]^T + bias[N] ----------
// m97 structure (known-good from round 2).
template <int OUT_BF16>
__global__ __launch_bounds__(256, 2)
void gemm_bt(const u16* __restrict__ A, const u16* __restrict__ B,
             const float* __restrict__ bias, u16* __restrict__ Cb,
             float* __restrict__ Cf, int M, int N, int K, int tilesN) {
  __shared__ u16 lA[128 * 32];
  __shared__ u16 lB[128 * 32];

  int bid = blockIdx.x;
  int cpx = gridDim.x >> 3;
  bid = (bid & 7) * cpx + (bid >> 3);

  const int tm = bid / tilesN, tn = bid % tilesN;
  const int row0 = tm * 128, col0 = tn * 128;
  const int tid = threadIdx.x;
  const int lane = tid & 63, wave = tid >> 6;

  const u16* Ag = A + (size_t)(row0 + (tid >> 2)) * K + (tid & 3) * 8;
  const u16* Bg = B + (size_t)(col0 + (tid >> 2)) * K + (tid & 3) * 8;
  const int ldsoff = tid * 8;

  const int wm = (wave >> 1) * 64, wn = (wave & 1) * 64;
  const int fr = lane & 15, fk = (lane >> 4) * 8;

  f32x4 acc[4][4] = {};

  for (int k0 = 0; k0 < K; k0 += 32) {
    __syncthreads();
    GLDS16(Ag + k0, &lA[ldsoff]);
    GLDS16(Ag + (size_t)64 * K + k0, &lA[2048 + ldsoff]);
    GLDS16(Bg + k0, &lB[ldsoff]);
    GLDS16(Bg + (size_t)64 * K + k0, &lB[2048 + ldsoff]);
    __syncthreads();

    s16x8 af[4], bfr[4];
#pragma unroll
    for (int i = 0; i < 4; ++i) af[i] = *(const s16x8*)&lA[(wm + i * 16 + fr) * 32 + fk];
#pragma unroll
    for (int i = 0; i < 4; ++i) bfr[i] = *(const s16x8*)&lB[(wn + i * 16 + fr) * 32 + fk];
#pragma unroll
    for (int i = 0; i < 4; ++i)
#pragma unroll
      for (int j = 0; j < 4; ++j) acc[i][j] = mfma16(af[i], bfr[j], acc[i][j]);
  }

#pragma unroll
  for (int i = 0; i < 4; ++i) {
#pragma unroll
    for (int r = 0; r < 4; ++r) {
      const int row = row0 + wm + i * 16 + (lane >> 4) * 4 + r;
#pragma unroll
      for (int j = 0; j < 4; ++j) {
        const int col = col0 + wn + j * 16 + fr;
        const float v = acc[i][j][r] + bias[col];
        if (OUT_BF16)
          Cb[(size_t)row * N + col] = f2bf(v);
        else
          Cf[(size_t)row * N + col] = v;
      }
    }
  }
}

// ---------------- V transpose: qkv V-section -> vt[bh][hd][kv] -------------
// grid = 128 bh * 16 t-tiles. Block stages a 64x64 tile through LDS.
__global__ __launch_bounds__(256)
void vtrans(const u16* __restrict__ qkv, u16* __restrict__ vt) {
  __shared__ u16 lT[64][68];  // pad 4 u16
  const int bid = blockIdx.x;
  const int bh = bid >> 4;
  const int tt = bid & 15;
  const int b = bh >> 4, h = bh & 15;
  const int tid = threadIdx.x;
  const int row = tid >> 2;        // 0..63
  const int cc = (tid & 3) * 16;   // 0,16,32,48

  const u16* src = qkv + (size_t)(b * 1024 + tt * 64 + row) * 3072 + 2048 + h * 64 + cc;
  *(u16x8*)&lT[row][cc] = *(const u16x8*)src;
  *(u16x8*)&lT[row][cc + 8] = *(const u16x8*)(src + 8);
  __syncthreads();

  u16 tmp[16];
#pragma unroll
  for (int i = 0; i < 16; ++i) tmp[i] = lT[cc + i][row];
  u16* dst = vt + (size_t)(bh * 64 + row) * 1024 + tt * 64 + cc;
  *(u16x8*)dst = *(u16x8*)&tmp[0];
  *(u16x8*)(dst + 8) = *(u16x8*)&tmp[8];
}

// ---------------- causal flash attention v2 --------------------------------
// No barriers, no K/V staging. Each wave owns 32 q rows of one (b,h).
// K A-frags + V^T B-frags read directly from global (L2-resident).
// Per-wave LDS only for the P round-trip ([32][72] u16, padded).
// Longest-first: qc = 31 - (w>>7) so 32-tile waves dispatch first.
__global__ __launch_bounds__(256)
void attn2(const u16* __restrict__ qkv, const u16* __restrict__ vt,
           const unsigned char* __restrict__ pmask,
           const float* __restrict__ scale_ptr, u16* __restrict__ outp) {
  __shared__ u16 lP[4][32 * 72];
  const int tid = threadIdx.x;
  const int lane = tid & 63, wave = tid >> 6;
  const int fr = lane & 15, grp = lane >> 4;
  const int w = blockIdx.x * 4 + wave;
  const int qc = 31 - (w >> 7);   // all 4 waves in a block share qc
  const int bh = w & 127;
  const int b = bh >> 4, h = bh & 15;
  const int qb = qc * 32;
  const float scale = scale_ptr[0];

  const u16* Kbase = qkv + (size_t)b * 1024 * 3072 + 1024 + h * 64;
  const u16* Vbase = vt + (size_t)bh * 64 * 1024;
  u16* lp = &lP[wave][0];

  // Q fragments (B-operand): col=q=g*16+fr, k=c*32+grp*8+j
  s16x8 qf[2][2];
#pragma unroll
  for (int g = 0; g < 2; ++g)
#pragma unroll
    for (int c = 0; c < 2; ++c)
      qf[g][c] = *(const s16x8*)(qkv + (size_t)(b * 1024 + qb + g * 16 + fr) * 3072 +
                                 h * 64 + c * 32 + grp * 8);

  f32x4 oacc[2][4] = {};
  float m_run[2] = {-1e30f, -1e30f};
  float l_run[2] = {0.0f, 0.0f};

  const int ntiles = (qc >> 1) + 1;
  for (int t = 0; t < ntiles; ++t) {
    const int kvb = t * 64;

    // ---- S^T = K * Q^T : st[f][g], q = qb+g*16+fr, kv = kvb+f*16+grp*4+r
    f32x4 st[4][2] = {};
#pragma unroll
    for (int f = 0; f < 4; ++f) {
      const u16* kp = Kbase + (size_t)(kvb + f * 16 + fr) * 3072 + grp * 8;
      s16x8 ka0 = *(const s16x8*)kp;
      s16x8 ka1 = *(const s16x8*)(kp + 32);
      st[f][0] = mfma16(ka0, qf[0][0], st[f][0]);
      st[f][0] = mfma16(ka1, qf[0][1], st[f][0]);
      st[f][1] = mfma16(ka0, qf[1][0], st[f][1]);
      st[f][1] = mfma16(ka1, qf[1][1], st[f][1]);
    }

    // ---- padding mask bytes for this tile's kv rows
    uint32_t pm[4];
#pragma unroll
    for (int f = 0; f < 4; ++f)
      pm[f] = *(const uint32_t*)(pmask + b * 1024 + kvb + f * 16 + grp * 4);

    // ---- online softmax per q-half
    float ar[2][4];
#pragma unroll
    for (int g = 0; g < 2; ++g) {
      const int q = qb + g * 16 + fr;
      float tmax = -1e30f;
#pragma unroll
      for (int f = 0; f < 4; ++f)
#pragma unroll
        for (int r = 0; r < 4; ++r) {
          const int kv = kvb + f * 16 + grp * 4 + r;
          float v = st[f][g][r] * scale;
          const bool pad = ((pm[f] >> (8 * r)) & 0xff) != 0;
          v = (kv > q || pad) ? -1e30f : v;
          st[f][g][r] = v;
          tmax = fmaxf(tmax, v);
        }
      tmax = fmaxf(tmax, __shfl_xor(tmax, 16));
      tmax = fmaxf(tmax, __shfl_xor(tmax, 32));
      const float m_new = fmaxf(m_run[g], tmax);
      const float alpha = __expf(m_run[g] - m_new);

      float rsum = 0.0f;
#pragma unroll
      for (int f = 0; f < 4; ++f)
#pragma unroll
        for (int rp = 0; rp < 2; ++rp) {
          const float p0 = __expf(st[f][g][rp * 2 + 0] - m_new);
          const float p1 = __expf(st[f][g][rp * 2 + 1] - m_new);
          rsum += p0 + p1;
          u16x2 pk;
          pk[0] = f2bf(p0);
          pk[1] = f2bf(p1);
          *(u16x2*)&lp[(g * 16 + fr) * 72 + f * 16 + grp * 4 + rp * 2] = pk;
        }
      rsum += __shfl_xor(rsum, 16);
      rsum += __shfl_xor(rsum, 32);
      l_run[g] = l_run[g] * alpha + rsum;
      m_run[g] = m_new;
#pragma unroll
      for (int r = 0; r < 4; ++r) ar[g][r] = __shfl(alpha, grp * 4 + r);
    }

    // ---- PV: A = P[q][kv] from lp, B = V^T rows from global vt
    s16x8 pa[2][2];
#pragma unroll
    for (int g = 0; g < 2; ++g)
#pragma unroll
      for (int kc = 0; kc < 2; ++kc)
        pa[g][kc] = *(const s16x8*)&lp[(g * 16 + fr) * 72 + kc * 32 + grp * 8];
#pragma unroll
    for (int nf = 0; nf < 4; ++nf) {
      const u16* vp = Vbase + (size_t)(nf * 16 + fr) * 1024 + kvb + grp * 8;
      s16x8 vb0 = *(const s16x8*)vp;
      s16x8 vb1 = *(const s16x8*)(vp + 32);
#pragma unroll
      for (int g = 0; g < 2; ++g) {
        f32x4 o = oacc[g][nf];
        o[0] *= ar[g][0];
        o[1] *= ar[g][1];
        o[2] *= ar[g][2];
        o[3] *= ar[g][3];
        o = mfma16(pa[g][0], vb0, o);
        o = mfma16(pa[g][1], vb1, o);
        oacc[g][nf] = o;
      }
    }
  }

  // ---- epilogue: q = qb+g*16+grp*4+r, hd = nf*16+fr
#pragma unroll
  for (int g = 0; g < 2; ++g) {
    float linv[4];
#pragma unroll
    for (int r = 0; r < 4; ++r) linv[r] = 1.0f / __shfl(l_run[g], grp * 4 + r);
#pragma unroll
    for (int nf = 0; nf < 4; ++nf)
#pragma unroll
      for (int r = 0; r < 4; ++r) {
        const int tq = qb + g * 16 + grp * 4 + r;
        outp[(size_t)(b * 1024 + tq) * 1024 + h * 64 + nf * 16 + fr] =
            f2bf(oacc[g][nf][r] * linv[r]);
      }
  }
}

// ---------------- launch ----------------------------------------------------
extern "C" void kernel_launch(void* const* d_in, const int* in_sizes, int n_in,
                              void* d_out, int out_size, void* d_ws, size_t ws_size,
                              hipStream_t stream) {
  const float* x = (const float*)d_in[0];
  const unsigned char* pmask = (const unsigned char*)d_in[1];
  const float* Wqkv = (const float*)d_in[2];
  const float* bqkv = (const float*)d_in[3];
  const float* Wproj = (const float*)d_in[4];
  const float* bproj = (const float*)d_in[5];
  const float* scale = (const float*)d_in[6];
  float* out = (float*)d_out;

  // workspace layout (bytes)
  char* ws = (char*)d_ws;
  u16* xb     = (u16*)(ws + 0);          // 16 MB; dead after gemm1
  u16* vtb    = (u16*)(ws + 0);          // aliases xb: vt[bh][hd][kv], 16 MB
  u16* wqkvb  = (u16*)(ws + 16777216);   // 6 MB
  u16* wprojb = (u16*)(ws + 23068672);   // 2 MB
  u16* qkv    = (u16*)(ws + 25165824);   // 48 MB
  u16* attno  = (u16*)(ws + 75497472);   // 16 MB
  if (ws_size < (size_t)92274688) return;

  cvt_f32_bf16<<<2048, 256, 0, stream>>>(x, xb, 8 * 1024 * 1024 / 4);
  cvt_f32_bf16<<<1024, 256, 0, stream>>>(Wqkv, wqkvb, 3 * 1024 * 1024 / 4);
  cvt_f32_bf16<<<512, 256, 0, stream>>>(Wproj, wprojb, 1024 * 1024 / 4);

  // QKV = x @ Wqkv^T + b : [8192, 3072] bf16
  gemm_bt<1><<<64 * 24, 256, 0, stream>>>(xb, wqkvb, bqkv, qkv, nullptr,
                                          8192, 3072, 1024, 24);
  // V -> vt[bh][hd][kv]  (xb is dead now; vtb aliases it)
  vtrans<<<2048, 256, 0, stream>>>(qkv, vtb);
  // attention
  attn2<<<1024, 256, 0, stream>>>(qkv, vtb, pmask, scale, attno);
  // out = attno @ Wproj^T + b : [8192, 1024] fp32
  gemm_bt<0><<<64 * 8, 256, 0, stream>>>(attno, wprojb, bproj, nullptr, out,
                                         8192, 1024, 1024, 8);
}

// Round 4
// 266.723 us; speedup vs baseline: 1.3780x; 1.0371x over previous
//
#include <hip/hip_runtime.h>
#include <cstdint>
#include <cstddef>

typedef unsigned short u16;
typedef __attribute__((ext_vector_type(2))) unsigned short u16x2;
typedef __attribute__((ext_vector_type(4))) unsigned short u16x4;
typedef __attribute__((ext_vector_type(8))) unsigned short u16x8;
typedef __attribute__((ext_vector_type(8))) short s16x8;
typedef __attribute__((ext_vector_type(4))) float f32x4;

// fp32 -> bf16 round-to-nearest-even
__device__ __forceinline__ u16 f2bf(float f) {
  uint32_t u = __float_as_uint(f);
  u += 0x7fffu + ((u >> 16) & 1u);
  return (u16)(u >> 16);
}

__device__ __forceinline__ f32x4 mfma16(s16x8 a, s16x8 b, f32x4 c) {
  return __builtin_amdgcn_mfma_f32_16x16x32_bf16(a, b, c, 0, 0, 0);
}

#define GLDS16(gp, lp) __builtin_amdgcn_global_load_lds(                     \
    (const __attribute__((address_space(1))) void*)(gp),                      \
    (__attribute__((address_space(3))) void*)(lp), 16, 0, 0)

// ---------------- fused fp32 -> bf16 conversion (x, Wqkv, Wproj) -----------
__global__ void cvt_all(const float* __restrict__ x, const float* __restrict__ wq,
                        const float* __restrict__ wp, u16* __restrict__ xb,
                        u16* __restrict__ wqb, u16* __restrict__ wpb) {
  const int n4x = 2097152, n4q = 786432, n4p = 262144;
  const int total = n4x + n4q + n4p;
  const int stride = gridDim.x * blockDim.x;
  for (int i = blockIdx.x * blockDim.x + threadIdx.x; i < total; i += stride) {
    const float* src;
    u16* dst;
    int j = i;
    if (j < n4x) {
      src = x; dst = xb;
    } else if (j < n4x + n4q) {
      j -= n4x; src = wq; dst = wqb;
    } else {
      j -= n4x + n4q; src = wp; dst = wpb;
    }
    f32x4 v = ((const f32x4*)src)[j];
    u16x4 o;
    o[0] = f2bf(v[0]); o[1] = f2bf(v[1]); o[2] = f2bf(v[2]); o[3] = f2bf(v[3]);
    ((u16x4*)dst)[j] = o;
  }
}

// ---------------- bf16 GEMM: C[M,N] = A[M,K] * B[N,K]^T + bias[N] ----------
// m97 structure (known-good; unchanged from round 3).
template <int OUT_BF16>
__global__ __launch_bounds__(256, 2)
void gemm_bt(const u16* __restrict__ A, const u16* __restrict__ B,
             const float* __restrict__ bias, u16* __restrict__ Cb,
             float* __restrict__ Cf, int M, int N, int K, int tilesN) {
  __shared__ u16 lA[128 * 32];
  __shared__ u16 lB[128 * 32];

  int bid = blockIdx.x;
  int cpx = gridDim.x >> 3;
  bid = (bid & 7) * cpx + (bid >> 3);

  const int tm = bid / tilesN, tn = bid % tilesN;
  const int row0 = tm * 128, col0 = tn * 128;
  const int tid = threadIdx.x;
  const int lane = tid & 63, wave = tid >> 6;

  const u16* Ag = A + (size_t)(row0 + (tid >> 2)) * K + (tid & 3) * 8;
  const u16* Bg = B + (size_t)(col0 + (tid >> 2)) * K + (tid & 3) * 8;
  const int ldsoff = tid * 8;

  const int wm = (wave >> 1) * 64, wn = (wave & 1) * 64;
  const int fr = lane & 15, fk = (lane >> 4) * 8;

  f32x4 acc[4][4] = {};

  for (int k0 = 0; k0 < K; k0 += 32) {
    __syncthreads();
    GLDS16(Ag + k0, &lA[ldsoff]);
    GLDS16(Ag + (size_t)64 * K + k0, &lA[2048 + ldsoff]);
    GLDS16(Bg + k0, &lB[ldsoff]);
    GLDS16(Bg + (size_t)64 * K + k0, &lB[2048 + ldsoff]);
    __syncthreads();

    s16x8 af[4], bfr[4];
#pragma unroll
    for (int i = 0; i < 4; ++i) af[i] = *(const s16x8*)&lA[(wm + i * 16 + fr) * 32 + fk];
#pragma unroll
    for (int i = 0; i < 4; ++i) bfr[i] = *(const s16x8*)&lB[(wn + i * 16 + fr) * 32 + fk];
#pragma unroll
    for (int i = 0; i < 4; ++i)
#pragma unroll
      for (int j = 0; j < 4; ++j) acc[i][j] = mfma16(af[i], bfr[j], acc[i][j]);
  }

#pragma unroll
  for (int i = 0; i < 4; ++i) {
#pragma unroll
    for (int r = 0; r < 4; ++r) {
      const int row = row0 + wm + i * 16 + (lane >> 4) * 4 + r;
#pragma unroll
      for (int j = 0; j < 4; ++j) {
        const int col = col0 + wn + j * 16 + fr;
        const float v = acc[i][j][r] + bias[col];
        if (OUT_BF16)
          Cb[(size_t)row * N + col] = f2bf(v);
        else
          Cf[(size_t)row * N + col] = v;
      }
    }
  }
}

// ---------------- V transpose: qkv V-section -> vt[bh][hd][kv] -------------
__global__ __launch_bounds__(256)
void vtrans(const u16* __restrict__ qkv, u16* __restrict__ vt) {
  __shared__ u16 lT[64][68];
  const int bid = blockIdx.x;
  const int bh = bid >> 4;
  const int tt = bid & 15;
  const int b = bh >> 4, h = bh & 15;
  const int tid = threadIdx.x;
  const int row = tid >> 2;
  const int cc = (tid & 3) * 16;

  const u16* src = qkv + (size_t)(b * 1024 + tt * 64 + row) * 3072 + 2048 + h * 64 + cc;
  *(u16x8*)&lT[row][cc] = *(const u16x8*)src;
  *(u16x8*)&lT[row][cc + 8] = *(const u16x8*)(src + 8);
  __syncthreads();

  u16 tmp[16];
#pragma unroll
  for (int i = 0; i < 16; ++i) tmp[i] = lT[cc + i][row];
  u16* dst = vt + (size_t)(bh * 64 + row) * 1024 + tt * 64 + cc;
  *(u16x8*)dst = *(u16x8*)&tmp[0];
  *(u16x8*)(dst + 8) = *(u16x8*)&tmp[8];
}

// ---------------- attention tile step --------------------------------------
// NF = number of 16-row kv fragments (4 -> 64 kv, 2 -> 32 kv).
// CAUSAL adds the per-element kv>q mask (only the diagonal tile needs it).
// Pad mask enters as additive bias pb[kv] in {0, -3e38} from LDS (one fma).
// T13 defer-max: skip rescale when tile max doesn't exceed m+8.
template <int NF, bool CAUSAL>
__device__ __forceinline__ void attn_step(
    const u16* __restrict__ Kbase, const u16* __restrict__ Vbase,
    const float* __restrict__ pb, u16* __restrict__ lp, int kvb, int qb,
    int fr, int grp, const s16x8 qf[2][2], f32x4 oacc[2][4], float m2[2],
    float l2[2], float cs) {
  // ---- S^T = K * Q^T  (C: row=kv, col=q)
  f32x4 st[NF][2];
#pragma unroll
  for (int f = 0; f < NF; ++f) {
    const u16* kp = Kbase + (size_t)(kvb + f * 16 + fr) * 3072 + grp * 8;
    s16x8 ka0 = *(const s16x8*)kp;
    s16x8 ka1 = *(const s16x8*)(kp + 32);
    f32x4 a0 = {0.f, 0.f, 0.f, 0.f}, a1 = {0.f, 0.f, 0.f, 0.f};
    a0 = mfma16(ka0, qf[0][0], a0);
    a0 = mfma16(ka1, qf[0][1], a0);
    a1 = mfma16(ka0, qf[1][0], a1);
    a1 = mfma16(ka1, qf[1][1], a1);
    st[f][0] = a0;
    st[f][1] = a1;
  }

  // ---- pad bias (broadcast LDS read, shared across g)
  f32x4 pbv[NF];
#pragma unroll
  for (int f = 0; f < NF; ++f)
    pbv[f] = *(const f32x4*)&pb[kvb + f * 16 + grp * 4];

  // ---- scale+bias(+causal), tile max per q-row
  float tm[2];
#pragma unroll
  for (int g = 0; g < 2; ++g) {
    const int q = qb + g * 16 + fr;
    float t = -3.0e38f;
#pragma unroll
    for (int f = 0; f < NF; ++f)
#pragma unroll
      for (int r = 0; r < 4; ++r) {
        float v = __builtin_fmaf(st[f][g][r], cs, pbv[f][r]);
        if (CAUSAL) {
          const int kv = kvb + f * 16 + grp * 4 + r;
          v = (kv > q) ? -3.0e38f : v;
        }
        st[f][g][r] = v;
        t = fmaxf(t, v);
      }
    t = fmaxf(t, __shfl_xor(t, 16));
    t = fmaxf(t, __shfl_xor(t, 32));
    tm[g] = t;
  }

  // ---- T13: rescale only when the max actually grows past THR=8
  const bool defer = __all((tm[0] <= m2[0] + 8.0f) && (tm[1] <= m2[1] + 8.0f)) != 0;
  if (!defer) {
#pragma unroll
    for (int g = 0; g < 2; ++g) {
      const float mn = fmaxf(m2[g], tm[g]);
      const float al = __expf(m2[g] - mn);
      m2[g] = mn;
      l2[g] *= al;
      float ar[4];
#pragma unroll
      for (int r = 0; r < 4; ++r) ar[r] = __shfl(al, grp * 4 + r);
#pragma unroll
      for (int nf = 0; nf < 4; ++nf) {
        oacc[g][nf][0] *= ar[0];
        oacc[g][nf][1] *= ar[1];
        oacc[g][nf][2] *= ar[2];
        oacc[g][nf][3] *= ar[3];
      }
    }
  }

  // ---- P = exp(v - m), pack to bf16 pairs via v_perm, accumulate l
#pragma unroll
  for (int g = 0; g < 2; ++g) {
    float rsum = 0.f;
#pragma unroll
    for (int f = 0; f < NF; ++f)
#pragma unroll
      for (int rp = 0; rp < 2; ++rp) {
        const float p0 = __expf(st[f][g][2 * rp] - m2[g]);
        const float p1 = __expf(st[f][g][2 * rp + 1] - m2[g]);
        rsum += p0 + p1;
        const uint32_t pk = __builtin_amdgcn_perm(
            __float_as_uint(p1) + 0x8000u, __float_as_uint(p0) + 0x8000u,
            0x07060302u);
        *(uint32_t*)&lp[(g * 16 + fr) * 72 + f * 16 + grp * 4 + 2 * rp] = pk;
      }
    rsum += __shfl_xor(rsum, 16);
    rsum += __shfl_xor(rsum, 32);
    l2[g] += rsum;
  }

  // ---- PV
  s16x8 pa[2][NF / 2];
#pragma unroll
  for (int g = 0; g < 2; ++g)
#pragma unroll
    for (int kc = 0; kc < NF / 2; ++kc)
      pa[g][kc] = *(const s16x8*)&lp[(g * 16 + fr) * 72 + kc * 32 + grp * 8];
#pragma unroll
  for (int nf = 0; nf < 4; ++nf) {
    const u16* vp = Vbase + (size_t)(nf * 16 + fr) * 1024 + kvb + grp * 8;
    s16x8 vb0 = *(const s16x8*)vp;
#pragma unroll
    for (int g = 0; g < 2; ++g) {
      f32x4 o = oacc[g][nf];
      o = mfma16(pa[g][0], vb0, o);
      if (NF == 4) o = mfma16(pa[g][1], *(const s16x8*)(vp + 32), o);
      oacc[g][nf] = o;
    }
  }
}

// ---------------- causal flash attention v3 --------------------------------
__global__ __launch_bounds__(256)
void attn3(const u16* __restrict__ qkv, const u16* __restrict__ vt,
           const unsigned char* __restrict__ pmask,
           const float* __restrict__ scale_ptr, u16* __restrict__ outp) {
  __shared__ u16 lP[4][32 * 72];
  __shared__ float lPb[1024];
  const int tid = threadIdx.x;
  const int lane = tid & 63, wave = tid >> 6;
  const int fr = lane & 15, grp = lane >> 4;
  const int w = blockIdx.x * 4 + wave;
  const int qc = 31 - (w >> 7);  // longest-first; all 4 waves share qc
  const int bh = w & 127;        // all 4 waves share b
  const int b = bh >> 4, h = bh & 15;
  const int qb = qc * 32;
  const float cs = scale_ptr[0];

  // stage pad bias for this b (shared by the whole block)
  for (int i = tid; i < 1024; i += 256)
    lPb[i] = pmask[b * 1024 + i] ? -3.0e38f : 0.0f;
  __syncthreads();

  const u16* Kbase = qkv + (size_t)b * 1024 * 3072 + 1024 + h * 64;
  const u16* Vbase = vt + (size_t)bh * 64 * 1024;
  u16* lp = &lP[wave][0];

  s16x8 qf[2][2];
#pragma unroll
  for (int g = 0; g < 2; ++g)
#pragma unroll
    for (int c = 0; c < 2; ++c)
      qf[g][c] = *(const s16x8*)(qkv + (size_t)(b * 1024 + qb + g * 16 + fr) * 3072 +
                                 h * 64 + c * 32 + grp * 8);

  f32x4 oacc[2][4] = {};
  float m2[2] = {-1e30f, -1e30f};
  float l2[2] = {0.0f, 0.0f};

  const int FT = qc >> 1;  // fully-unmasked 64-kv tiles
  for (int t = 0; t < FT; ++t)
    attn_step<4, false>(Kbase, Vbase, lPb, lp, t * 64, qb, fr, grp, qf, oacc, m2, l2, cs);
  if (qc & 1)
    attn_step<2, false>(Kbase, Vbase, lPb, lp, qb - 32, qb, fr, grp, qf, oacc, m2, l2, cs);
  attn_step<2, true>(Kbase, Vbase, lPb, lp, qb, qb, fr, grp, qf, oacc, m2, l2, cs);

  // ---- epilogue: q = qb+g*16+grp*4+r, hd = nf*16+fr
#pragma unroll
  for (int g = 0; g < 2; ++g) {
    float linv[4];
#pragma unroll
    for (int r = 0; r < 4; ++r) linv[r] = 1.0f / __shfl(l2[g], grp * 4 + r);
#pragma unroll
    for (int nf = 0; nf < 4; ++nf)
#pragma unroll
      for (int r = 0; r < 4; ++r) {
        const int tq = qb + g * 16 + grp * 4 + r;
        outp[(size_t)(b * 1024 + tq) * 1024 + h * 64 + nf * 16 + fr] =
            f2bf(oacc[g][nf][r] * linv[r]);
      }
  }
}

// ---------------- launch ----------------------------------------------------
extern "C" void kernel_launch(void* const* d_in, const int* in_sizes, int n_in,
                              void* d_out, int out_size, void* d_ws, size_t ws_size,
                              hipStream_t stream) {
  const float* x = (const float*)d_in[0];
  const unsigned char* pmask = (const unsigned char*)d_in[1];
  const float* Wqkv = (const float*)d_in[2];
  const float* bqkv = (const float*)d_in[3];
  const float* Wproj = (const float*)d_in[4];
  const float* bproj = (const float*)d_in[5];
  const float* scale = (const float*)d_in[6];
  float* out = (float*)d_out;

  char* ws = (char*)d_ws;
  u16* xb     = (u16*)(ws + 0);          // 16 MB; dead after gemm1
  u16* vtb    = (u16*)(ws + 0);          // aliases xb: vt[bh][hd][kv]
  u16* wqkvb  = (u16*)(ws + 16777216);   // 6 MB
  u16* wprojb = (u16*)(ws + 23068672);   // 2 MB
  u16* qkv    = (u16*)(ws + 25165824);   // 48 MB
  u16* attno  = (u16*)(ws + 75497472);   // 16 MB
  if (ws_size < (size_t)92274688) return;

  cvt_all<<<2048, 256, 0, stream>>>(x, Wqkv, Wproj, xb, wqkvb, wprojb);

  // QKV = x @ Wqkv^T + b : [8192, 3072] bf16
  gemm_bt<1><<<64 * 24, 256, 0, stream>>>(xb, wqkvb, bqkv, qkv, nullptr,
                                          8192, 3072, 1024, 24);
  // V -> vt[bh][hd][kv]
  vtrans<<<2048, 256, 0, stream>>>(qkv, vtb);
  // attention
  attn3<<<1024, 256, 0, stream>>>(qkv, vtb, pmask, scale, attno);
  // out = attno @ Wproj^T + b : [8192, 1024] fp32
  gemm_bt<0><<<64 * 8, 256, 0, stream>>>(attno, wprojb, bproj, nullptr, out,
                                         8192, 1024, 1024, 8);
}